// Round 4
// baseline (943.379 us; speedup 1.0000x reference)
//
#include <hip/hip_runtime.h>
#include <math.h>

#define TT 512
#define BB 128
#define KK 9

// ---------------------------------------------------------------------------
// fast activations: v_exp_f32 / v_rcp_f32 based (~1 ulp each)
// ---------------------------------------------------------------------------
__device__ __forceinline__ float fast_sigmoid(float x) {
    const float LOG2E = 1.4426950408889634f;
    float e = __builtin_amdgcn_exp2f(-x * LOG2E);
    return __builtin_amdgcn_rcpf(1.0f + e);
}
__device__ __forceinline__ float fast_tanh(float x) {
    const float LOG2E = 1.4426950408889634f;
    float a = fabsf(x);
    float e = __builtin_amdgcn_exp2f(-2.0f * a * LOG2E);   // in (0,1]
    float t = (1.0f - e) * __builtin_amdgcn_rcpf(1.0f + e);
    return copysignf(t, x);
}

// ---------------------------------------------------------------------------
// G: input projection. Only change vs proven R3: occupancy 3 -> 4 blocks/CU
// (LDS 33.8KB x4 = 135KB fits; VGPR 84 <= 128). Theory: gemm is ~2.5x its
// VALU floor; prime suspect is emb-gather latency at 12 waves/CU -> 16.
// Also makes 4096 blocks an exact 4 rounds at 4/CU.
// ---------------------------------------------------------------------------
__global__ __launch_bounds__(256, 4) void input_gemm(
    const int* __restrict__ x, const float* __restrict__ emb,
    const float* __restrict__ w_ih_f, const float* __restrict__ w_ih_b,
    const float* __restrict__ b_ih_f, const float* __restrict__ b_hh_f,
    const float* __restrict__ b_ih_b, const float* __restrict__ b_hh_b,
    float* __restrict__ buf_f, float* __restrict__ buf_b,
    int t0f, int t0b)
{
    const int dir = blockIdx.z;
    const int s   = blockIdx.x;           // local timestep within chunk
    const int n0  = blockIdx.y * 128;     // gate tile base
    const int t   = (dir ? t0b : t0f) + s;
    const float* w  = dir ? w_ih_b : w_ih_f;
    const float* bi = dir ? b_ih_b : b_ih_f;
    const float* bh = dir ? b_hh_b : b_hh_f;
    float* dst = dir ? buf_b : buf_f;

    __shared__ __align__(16) float As[32][132];   // [k][row] 16.9 KB
    __shared__ __align__(16) float Bs[32][132];   // [k][gate] 16.9 KB

    const int tid  = threadIdx.x;
    const int lrow = tid >> 3;            // 0..31
    const int k4   = (tid & 7) * 4;       // 0..28

    int tokr[4];
    #pragma unroll
    for (int p = 0; p < 4; p++) tokr[p] = x[(p * 32 + lrow) * TT + t];

    const int tx = tid & 15;
    const int ty = tid >> 4;

    float acc[8][8];
    #pragma unroll
    for (int i = 0; i < 8; i++)
        #pragma unroll
        for (int j = 0; j < 8; j++) acc[i][j] = 0.0f;

    float4 aS[4], bS[4];
    #pragma unroll
    for (int p = 0; p < 4; p++) {
        aS[p] = *(const float4*)(emb + (size_t)tokr[p] * 128 + k4);
        bS[p] = *(const float4*)(w + (size_t)(n0 + p * 32 + lrow) * 128 + k4);
    }

    for (int kc = 0; kc < 128; kc += 32) {
        __syncthreads();                 // prev chunk's reads done
        #pragma unroll
        for (int p = 0; p < 4; p++) {
            const int row = p * 32 + lrow;
            As[k4 + 0][row] = aS[p].x; As[k4 + 1][row] = aS[p].y;
            As[k4 + 2][row] = aS[p].z; As[k4 + 3][row] = aS[p].w;
            Bs[k4 + 0][row] = bS[p].x; Bs[k4 + 1][row] = bS[p].y;
            Bs[k4 + 2][row] = bS[p].z; Bs[k4 + 3][row] = bS[p].w;
        }
        __syncthreads();                 // staging visible
        if (kc + 32 < 128) {             // prefetch next chunk (hidden by compute)
            #pragma unroll
            for (int p = 0; p < 4; p++) {
                aS[p] = *(const float4*)(emb + (size_t)tokr[p] * 128 + kc + 32 + k4);
                bS[p] = *(const float4*)(w + (size_t)(n0 + p * 32 + lrow) * 128 + kc + 32 + k4);
            }
        }
        #pragma unroll 8
        for (int k = 0; k < 32; k++) {
            float4 af0 = *(const float4*)&As[k][ty * 8];
            float4 af1 = *(const float4*)&As[k][ty * 8 + 4];
            float4 bf0 = *(const float4*)&Bs[k][tx * 8];
            float4 bf1 = *(const float4*)&Bs[k][tx * 8 + 4];
            float a_[8] = {af0.x, af0.y, af0.z, af0.w, af1.x, af1.y, af1.z, af1.w};
            float b_[8] = {bf0.x, bf0.y, bf0.z, bf0.w, bf1.x, bf1.y, bf1.z, bf1.w};
            #pragma unroll
            for (int i = 0; i < 8; i++)
                #pragma unroll
                for (int j = 0; j < 8; j++)
                    acc[i][j] += a_[i] * b_[j];
        }
    }

    const int nbase = n0 + tx * 8;
    float bias[8];
    #pragma unroll
    for (int j = 0; j < 8; j++) {
        int n = nbase + j;
        bias[j] = bi[n] + bh[n];
    }
    #pragma unroll
    for (int i = 0; i < 8; i++) {
        int brow = ty * 8 + i;
        float* o = dst + ((size_t)s * 128 + brow) * 512 + nbase;
        float4 v0, v1;
        v0.x = acc[i][0] + bias[0]; v0.y = acc[i][1] + bias[1];
        v0.z = acc[i][2] + bias[2]; v0.w = acc[i][3] + bias[3];
        v1.x = acc[i][4] + bias[4]; v1.y = acc[i][5] + bias[5];
        v1.z = acc[i][6] + bias[6]; v1.w = acc[i][7] + bias[7];
        *(float4*)o = v0;
        *(float4*)(o + 4) = v1;
    }
}

// ---------------------------------------------------------------------------
// L: LSTM recurrence + IN-LOOP POST-BARRIER emissions (R13) + fused Viterbi.
//
// R12 lesson: work INSIDE the per-step barrier region (pre-activation,
// 4-way-conflicted LDS, shfl chained into the serial path) costs x512.
// R13 placement: the emission dot for h_t runs AFTER the step's
// __syncthreads(), in the proven fire-and-forget slot (where xw prefetch
// and the old h_all store lived). Differences vs R12's failure:
//   - post-barrier: not on the dot->act->c->h serial chain
//   - W_tag slice held in REGISTERS (8 floats, threads 0..143 only)
//   - h read as el*4 / 64+el*4 b128 pairs: 2-way bank alias = free (m136)
//   - reads h_lds[p^1]; next step writes h_lds[p] -> no WAR race
//   - 4-level shfl_xor within 16-lane groups (16-aligned, no wave straddle)
// h_all is DELETED (was 33.5MB W + 67MB R + 45us of LDS-issue in phase C).
// Both dirs stream raw partials to emF/emB (global, fire-and-forget);
// tail: pairwise flag sync (proven) -> fold emF+emB+bias -> Viterbi.
// ---------------------------------------------------------------------------
__global__ __launch_bounds__(512, 2) void lstm_fused(
    const float* __restrict__ buf_f, const float* __restrict__ buf_b,
    const float* __restrict__ w_hh_f, const float* __restrict__ w_hh_b,
    float* __restrict__ h_state, float* __restrict__ c_state,
    const float* __restrict__ W_tag, const float* __restrict__ b_tag,
    const float* __restrict__ start_trans, const float* __restrict__ end_trans,
    const float* __restrict__ trans,
    float* __restrict__ emF, float* __restrict__ emB,
    unsigned* __restrict__ flags, int* __restrict__ out,
    int t0f, int t0b, int C, int init, int tail)
{
    const int dir = blockIdx.x >> 7;
    const int b   = blockIdx.x & 127;
    const int j   = threadIdx.x;
    const int w_  = j >> 6;          // wave id 0..7
    const int l   = j & 63;
    const int m   = l >> 2;          // group 0..15
    const int q   = l & 3;           // gate: 0=i 1=f 2=g 3=o
    const int k   = w_ * 16 + m;     // h index 0..127
    const int r   = q * 128 + k;     // gate row in [0,512)

    // forward snapshot of the pairwise counter BEFORE any real work; the
    // backward partner cannot finish its recurrence before this executes.
    unsigned snap = 0u;
    if (tail && dir == 0 && j == 0)
        snap = __hip_atomic_load(&flags[b], __ATOMIC_RELAXED, __HIP_MEMORY_SCOPE_AGENT);

    const float* whh = dir ? w_hh_b : w_hh_f;
    float wR[128];
    #pragma unroll
    for (int qq = 0; qq < 32; qq++) {
        float4 v = *(const float4*)(whh + (size_t)r * 128 + qq * 4);
        wR[4*qq+0] = v.x; wR[4*qq+1] = v.y; wR[4*qq+2] = v.z; wR[4*qq+3] = v.w;
    }

    __shared__ __align__(16) float h_lds[2][128];    // 1 KB
    __shared__ __align__(16) float em_s[TT * KK];    // 18.4 KB
    __shared__ unsigned char bp[TT][KK];             // 4.6 KB  => ~24 KB total

    // emission assignment: threads 0..143 = 9 tags x 16 lanes (16-aligned:
    // every group lives inside one wave; shfl_xor 1/2/4/8 stays in-group)
    const int  eg  = j >> 4;             // tag 0..8 valid
    const int  el  = j & 15;             // lane in group
    const bool edo = (eg < KK);
    float wE[8];
    if (edo) {
        #pragma unroll
        for (int u = 0; u < 4; u++) {
            wE[u]     = W_tag[eg * 256 + dir * 128 + el * 4 + u];
            wE[4 + u] = W_tag[eg * 256 + dir * 128 + 64 + el * 4 + u];
        }
    }
    float* emdst = (dir ? emB : emF) + (size_t)b * TT * KK;

    float c;
    if (init) {
        c = 0.0f;
        if (q == 0) h_lds[0][k] = 0.0f;
    } else {
        c = c_state[((size_t)dir * 128 + b) * 128 + k];
        if (q == 0) h_lds[0][k] = h_state[((size_t)dir * 128 + b) * 128 + k];
    }
    __syncthreads();                     // h_lds[0] visible

    const float* buf = dir ? buf_b : buf_f;
    const int t0     = dir ? t0b : t0f;
    const int  tl0   = dir ? (C - 1) : 0;
    const long lstep = dir ? -(long)(128 * 512) : (long)(128 * 512);

    const float* xp = buf + ((size_t)tl0 * 128 + b) * 512 + r;
    float xw = *xp;
    float h_reg = 0.0f;

    for (int s = 0; s < C; s++) {
        const int t = t0 + (dir ? (C - 1 - s) : s);
        const int p = s & 1;
        const float* hprev = h_lds[p];

        float a0 = 0.f, a1 = 0.f, a2 = 0.f, a3 = 0.f;
        #pragma unroll
        for (int qq = 0; qq < 32; qq++) {
            float4 h4 = *(const float4*)&hprev[4 * qq];
            a0 += wR[4*qq+0] * h4.x;
            a1 += wR[4*qq+1] * h4.y;
            a2 += wR[4*qq+2] * h4.z;
            a3 += wR[4*qq+3] * h4.w;
        }
        float pre = xw + ((a0 + a1) + (a2 + a3));

        float act = (q == 2) ? fast_tanh(pre) : fast_sigmoid(pre);

        float f_ = __shfl_xor(act, 1);   // q0 <- q1 (f)
        float g_ = __shfl_xor(act, 2);   // q0 <- q2 (g)
        float o_ = __shfl_xor(act, 3);   // q0 <- q3 (o)

        c = f_ * c + act * g_;           // act == i on q0
        h_reg = o_ * fast_tanh(c);
        if (q == 0) h_lds[p ^ 1][k] = h_reg;

        __syncthreads();                 // h_t visible to all waves

        // ---- post-barrier fire-and-forget slot (off the serial chain) ----
        if (s + 1 < C) { xp += lstep; xw = *xp; }   // next x (global latency)
        if (edo) {                                   // emission of h_t
            const float4 hA = *(const float4*)&h_lds[p ^ 1][el * 4];
            const float4 hB = *(const float4*)&h_lds[p ^ 1][64 + el * 4];
            float pp = hA.x * wE[0] + hA.y * wE[1] + hA.z * wE[2] + hA.w * wE[3]
                     + hB.x * wE[4] + hB.y * wE[5] + hB.z * wE[6] + hB.w * wE[7];
            pp += __shfl_xor(pp, 8);
            pp += __shfl_xor(pp, 4);
            pp += __shfl_xor(pp, 2);
            pp += __shfl_xor(pp, 1);
            if (el == 0) emdst[(size_t)t * KK + eg] = pp;
        }
    }

    if (q == 0) {
        h_state[((size_t)dir * 128 + b) * 128 + k] = h_reg;
        c_state[((size_t)dir * 128 + b) * 128 + k] = c;
    }

    if (!tail) return;                   // chunked path: only last round decodes

    if (dir == 1) {                      // backward: publish and exit
        __syncthreads();                 // all waves reached here; compiler
                                         // drains vmcnt before s_barrier
        if (j == 0) {
            __threadfence();             // agent-scope: emB visible device-wide
            __hip_atomic_fetch_add(&flags[b], 1u, __ATOMIC_RELEASE,
                                   __HIP_MEMORY_SCOPE_AGENT);
        }
        return;
    }

    // forward: wait for backward partner, fold emF+emB+bias into LDS
    if (j == 0) {
        while (__hip_atomic_load(&flags[b], __ATOMIC_ACQUIRE,
                                 __HIP_MEMORY_SCOPE_AGENT) == snap)
            __builtin_amdgcn_s_sleep(1);
    }
    __syncthreads();                     // acquire visible to whole block
    {
        const float* eF = emF + (size_t)b * TT * KK;
        const float* eB = emB + (size_t)b * TT * KK;
        for (int f = j; f < TT * KK; f += 512)
            em_s[f] = eF[f] + eB[f] + b_tag[f % KK];
    }
    __syncthreads();

    // ---- phase V: Viterbi decode on wave 0 (unchanged, proven) ------------
    if (j < 64) {
        const int lane = j;

        float trans_col[KK];
        float score = -1e30f;
        if (lane < KK) {
            #pragma unroll
            for (int i = 0; i < KK; i++) trans_col[i] = trans[i * KK + lane];
            score = start_trans[lane] + em_s[lane];
        }

        float em_cur = (lane < KK) ? em_s[KK + lane] : 0.0f;   // t=1
        for (int t = 1; t < TT; t++) {
            float em_next = (t + 1 < TT && lane < KK) ? em_s[(t + 1) * KK + lane] : 0.0f;

            float my = (lane < KK) ? score : -1e30f;
            float cand[KK];
            #pragma unroll
            for (int i = 0; i < KK; i++) cand[i] = __shfl(my, i) + trans_col[i];

            float v01, v23, v45, v67, v03, v47, v07, vb_;
            int   i01, i23, i45, i67, i03, i47, i07, ib_;
            {
                bool gt;
                gt = cand[1] > cand[0]; v01 = gt ? cand[1] : cand[0]; i01 = gt ? 1 : 0;
                gt = cand[3] > cand[2]; v23 = gt ? cand[3] : cand[2]; i23 = gt ? 3 : 2;
                gt = cand[5] > cand[4]; v45 = gt ? cand[5] : cand[4]; i45 = gt ? 5 : 4;
                gt = cand[7] > cand[6]; v67 = gt ? cand[7] : cand[6]; i67 = gt ? 7 : 6;
                gt = v23 > v01; v03 = gt ? v23 : v01; i03 = gt ? i23 : i01;
                gt = v67 > v45; v47 = gt ? v67 : v45; i47 = gt ? i67 : i45;
                gt = v47 > v03; v07 = gt ? v47 : v03; i07 = gt ? i47 : i03;
                gt = cand[8] > v07; vb_ = gt ? cand[8] : v07; ib_ = gt ? 8 : i07;
            }

            if (lane < KK) {
                bp[t][lane] = (unsigned char)ib_;
                score = vb_ + em_cur;
            }
            em_cur = em_next;
        }

        float fin = (lane < KK) ? (score + end_trans[lane]) : -1e30f;
        float farr[KK];
        #pragma unroll
        for (int jx = 0; jx < KK; jx++) farr[jx] = __shfl(fin, jx);
        float v01, v23, v45, v67, v03, v47, v07, vb_;
        int   i01, i23, i45, i67, i03, i47, i07, bj;
        {
            bool gt;
            gt = farr[1] > farr[0]; v01 = gt ? farr[1] : farr[0]; i01 = gt ? 1 : 0;
            gt = farr[3] > farr[2]; v23 = gt ? farr[3] : farr[2]; i23 = gt ? 3 : 2;
            gt = farr[5] > farr[4]; v45 = gt ? farr[5] : farr[4]; i45 = gt ? 5 : 4;
            gt = farr[7] > farr[6]; v67 = gt ? farr[7] : farr[6]; i67 = gt ? 7 : 6;
            gt = v23 > v01; v03 = gt ? v23 : v01; i03 = gt ? i23 : i01;
            gt = v67 > v45; v47 = gt ? v67 : v45; i47 = gt ? i67 : i45;
            gt = v47 > v03; v07 = gt ? v47 : v03; i07 = gt ? i47 : i03;
            gt = farr[8] > v07; vb_ = gt ? farr[8] : v07; bj = gt ? 8 : i07;
        }

        if (lane == 0) {
            int tag = bj;
            out[b * TT + (TT - 1)] = tag;
            for (int t = TT - 1; t >= 1; t--) {
                tag = bp[t][tag];
                out[b * TT + t - 1] = tag;
            }
        }
    }
}

// ---------------------------------------------------------------------------
extern "C" void kernel_launch(void* const* d_in, const int* in_sizes, int n_in,
                              void* d_out, int out_size, void* d_ws, size_t ws_size,
                              hipStream_t stream)
{
    const int*   x       = (const int*)  d_in[0];
    const float* emb     = (const float*)d_in[1];
    const float* w_ih_f  = (const float*)d_in[2];
    const float* w_hh_f  = (const float*)d_in[3];
    const float* b_ih_f  = (const float*)d_in[4];
    const float* b_hh_f  = (const float*)d_in[5];
    const float* w_ih_b  = (const float*)d_in[6];
    const float* w_hh_b  = (const float*)d_in[7];
    const float* b_ih_b  = (const float*)d_in[8];
    const float* b_hh_b  = (const float*)d_in[9];
    const float* W_tag   = (const float*)d_in[10];
    const float* b_tag   = (const float*)d_in[11];
    const float* start_t = (const float*)d_in[12];
    const float* end_t   = (const float*)d_in[13];
    const float* trans   = (const float*)d_in[14];
    int* out = (int*)d_out;

    const size_t em_elems    = (size_t)BB * TT * KK;   // 2.25 MB per buffer
    const size_t state_elems = (size_t)2 * 128 * 128;

    // C=512 preferred: single lstm dispatch (fixed dispatch cost ~55us).
    int C = 32;
    const int cands[5] = {512, 256, 128, 64, 32};
    for (int ci = 0; ci < 5; ci++) {
        size_t need = ((size_t)2 * cands[ci] * BB * 512
                       + 2 * em_elems + 2 * state_elems) * sizeof(float) + 1024;
        if (ws_size >= need) { C = cands[ci]; break; }
    }

    float* buf_f   = (float*)d_ws;                        // C*128*512
    float* buf_b   = buf_f + (size_t)C * BB * 512;        // C*128*512
    float* emF     = buf_b + (size_t)C * BB * 512;        // B*T*9
    float* emB     = emF + em_elems;                      // B*T*9
    float* h_state = emB + em_elems;                      // 2*128*128
    float* c_state = h_state + state_elems;               // 2*128*128
    unsigned* flags = (unsigned*)(c_state + state_elems); // 128 monotonic ctrs

    const int rounds = TT / C;
    for (int r = 0; r < rounds; r++) {
        const int t0f = r * C;
        const int t0b = TT - (r + 1) * C;
        dim3 gg(C, 4, 2);
        input_gemm<<<gg, dim3(256), 0, stream>>>(
            x, emb, w_ih_f, w_ih_b, b_ih_f, b_hh_f, b_ih_b, b_hh_b,
            buf_f, buf_b, t0f, t0b);
        lstm_fused<<<dim3(256), dim3(512), 0, stream>>>(
            buf_f, buf_b, w_hh_f, w_hh_b,
            h_state, c_state,
            W_tag, b_tag, start_t, end_t, trans,
            emF, emB, flags, out,
            t0f, t0b, C, (r == 0) ? 1 : 0, (r == rounds - 1) ? 1 : 0);
    }
}

// Round 5
// 847.211 us; speedup vs baseline: 1.1135x; 1.1135x over previous
//
#include <hip/hip_runtime.h>
#include <math.h>

#define TT 512
#define BB 128
#define KK 9

// ---------------------------------------------------------------------------
// fast activations: v_exp_f32 / v_rcp_f32 based (~1 ulp each)
// ---------------------------------------------------------------------------
__device__ __forceinline__ float fast_sigmoid(float x) {
    const float LOG2E = 1.4426950408889634f;
    float e = __builtin_amdgcn_exp2f(-x * LOG2E);
    return __builtin_amdgcn_rcpf(1.0f + e);
}
__device__ __forceinline__ float fast_tanh(float x) {
    const float LOG2E = 1.4426950408889634f;
    float a = fabsf(x);
    float e = __builtin_amdgcn_exp2f(-2.0f * a * LOG2E);   // in (0,1]
    float t = (1.0f - e) * __builtin_amdgcn_rcpf(1.0f + e);
    return copysignf(t, x);
}

// ---------------------------------------------------------------------------
// G: input projection, BK=32 chunked, (256,3) occupancy (R4 lesson: 4/CU
// regressed +65us). R14 change: B-fragment read split tx*8 -> {tx*4,
// 64+tx*4}. Old pattern Bs[k][tx*8] hit banks (8tx)%32 = 4 banks for 16
// txs = 4-way conflict (1.58x, m136) on half the fragment reads; G is
// LDS-BW-bound (0.5 B/FLOP = exactly the 128 B/cyc ceiling), so this
// multiplier stretched G directly (SQ_LDS_BANK_CONFLICT was 1.47e7).
// New pattern: banks stride 4, 2-way alias = free. Output column map
// remapped to match (thread owns gates nb0+0..3, nb1+0..3).
// ---------------------------------------------------------------------------
__global__ __launch_bounds__(256, 3) void input_gemm(
    const int* __restrict__ x, const float* __restrict__ emb,
    const float* __restrict__ w_ih_f, const float* __restrict__ w_ih_b,
    const float* __restrict__ b_ih_f, const float* __restrict__ b_hh_f,
    const float* __restrict__ b_ih_b, const float* __restrict__ b_hh_b,
    float* __restrict__ buf_f, float* __restrict__ buf_b,
    int t0f, int t0b)
{
    const int dir = blockIdx.z;
    const int s   = blockIdx.x;           // local timestep within chunk
    const int n0  = blockIdx.y * 128;     // gate tile base
    const int t   = (dir ? t0b : t0f) + s;
    const float* w  = dir ? w_ih_b : w_ih_f;
    const float* bi = dir ? b_ih_b : b_ih_f;
    const float* bh = dir ? b_hh_b : b_hh_f;
    float* dst = dir ? buf_b : buf_f;

    __shared__ __align__(16) float As[32][132];   // [k][row] 16.9 KB
    __shared__ __align__(16) float Bs[32][132];   // [k][gate] 16.9 KB

    const int tid  = threadIdx.x;
    const int lrow = tid >> 3;            // 0..31
    const int k4   = (tid & 7) * 4;       // 0..28

    int tokr[4];
    #pragma unroll
    for (int p = 0; p < 4; p++) tokr[p] = x[(p * 32 + lrow) * TT + t];

    const int tx = tid & 15;
    const int ty = tid >> 4;

    float acc[8][8];
    #pragma unroll
    for (int i = 0; i < 8; i++)
        #pragma unroll
        for (int j = 0; j < 8; j++) acc[i][j] = 0.0f;

    float4 aS[4], bS[4];
    #pragma unroll
    for (int p = 0; p < 4; p++) {
        aS[p] = *(const float4*)(emb + (size_t)tokr[p] * 128 + k4);
        bS[p] = *(const float4*)(w + (size_t)(n0 + p * 32 + lrow) * 128 + k4);
    }

    for (int kc = 0; kc < 128; kc += 32) {
        __syncthreads();                 // prev chunk's reads done
        #pragma unroll
        for (int p = 0; p < 4; p++) {
            const int row = p * 32 + lrow;
            As[k4 + 0][row] = aS[p].x; As[k4 + 1][row] = aS[p].y;
            As[k4 + 2][row] = aS[p].z; As[k4 + 3][row] = aS[p].w;
            Bs[k4 + 0][row] = bS[p].x; Bs[k4 + 1][row] = bS[p].y;
            Bs[k4 + 2][row] = bS[p].z; Bs[k4 + 3][row] = bS[p].w;
        }
        __syncthreads();                 // staging visible
        if (kc + 32 < 128) {             // prefetch next chunk (hidden by compute)
            #pragma unroll
            for (int p = 0; p < 4; p++) {
                aS[p] = *(const float4*)(emb + (size_t)tokr[p] * 128 + kc + 32 + k4);
                bS[p] = *(const float4*)(w + (size_t)(n0 + p * 32 + lrow) * 128 + kc + 32 + k4);
            }
        }
        #pragma unroll 8
        for (int k = 0; k < 32; k++) {
            float4 af0 = *(const float4*)&As[k][ty * 8];
            float4 af1 = *(const float4*)&As[k][ty * 8 + 4];
            float4 bf0 = *(const float4*)&Bs[k][tx * 4];        // banks: 2-way, free
            float4 bf1 = *(const float4*)&Bs[k][64 + tx * 4];   // banks: 2-way, free
            float a_[8] = {af0.x, af0.y, af0.z, af0.w, af1.x, af1.y, af1.z, af1.w};
            float b_[8] = {bf0.x, bf0.y, bf0.z, bf0.w, bf1.x, bf1.y, bf1.z, bf1.w};
            #pragma unroll
            for (int i = 0; i < 8; i++)
                #pragma unroll
                for (int j = 0; j < 8; j++)
                    acc[i][j] += a_[i] * b_[j];
        }
    }

    // thread owns gate columns nb0+0..3 (acc[][0..3]) and nb1+0..3 (acc[][4..7])
    const int nb0 = n0 + tx * 4;
    const int nb1 = n0 + 64 + tx * 4;
    float bias[8];
    #pragma unroll
    for (int j = 0; j < 4; j++) {
        bias[j]     = bi[nb0 + j] + bh[nb0 + j];
        bias[4 + j] = bi[nb1 + j] + bh[nb1 + j];
    }
    #pragma unroll
    for (int i = 0; i < 8; i++) {
        int brow = ty * 8 + i;
        float* o = dst + ((size_t)s * 128 + brow) * 512;
        float4 v0, v1;
        v0.x = acc[i][0] + bias[0]; v0.y = acc[i][1] + bias[1];
        v0.z = acc[i][2] + bias[2]; v0.w = acc[i][3] + bias[3];
        v1.x = acc[i][4] + bias[4]; v1.y = acc[i][5] + bias[5];
        v1.z = acc[i][6] + bias[6]; v1.w = acc[i][7] + bias[7];
        *(float4*)(o + nb0) = v0;
        *(float4*)(o + nb1) = v1;
    }
}

// ---------------------------------------------------------------------------
// L: LSTM recurrence (R0-exact barrier region) + tail phase C emissions +
// fused Viterbi. VERBATIM the proven R3 kernel (856 us baseline).
// h_all layout [dir][b][t][k]: private contiguous 256 KB per block;
// phase C stages it coalesced into padded LDS then does LDS dots.
// ---------------------------------------------------------------------------
__global__ __launch_bounds__(512, 2) void lstm_fused(
    const float* __restrict__ buf_f, const float* __restrict__ buf_b,
    const float* __restrict__ w_hh_f, const float* __restrict__ w_hh_b,
    float* __restrict__ h_all,
    float* __restrict__ h_state, float* __restrict__ c_state,
    const float* __restrict__ W_tag, const float* __restrict__ b_tag,
    const float* __restrict__ start_trans, const float* __restrict__ end_trans,
    const float* __restrict__ trans,
    float* __restrict__ emB, unsigned* __restrict__ flags,
    int* __restrict__ out,
    int t0f, int t0b, int C, int init, int tail)
{
    const int dir = blockIdx.x >> 7;
    const int b   = blockIdx.x & 127;
    const int j   = threadIdx.x;
    const int w_  = j >> 6;          // wave id 0..7
    const int l   = j & 63;
    const int m   = l >> 2;          // group 0..15
    const int q   = l & 3;           // gate: 0=i 1=f 2=g 3=o
    const int k   = w_ * 16 + m;     // h index 0..127
    const int r   = q * 128 + k;     // gate row in [0,512)

    // forward snapshot of the pairwise counter BEFORE any real work; the
    // backward partner cannot finish its recurrence before this executes.
    unsigned snap = 0u;
    if (tail && dir == 0 && j == 0)
        snap = __hip_atomic_load(&flags[b], __ATOMIC_RELAXED, __HIP_MEMORY_SCOPE_AGENT);

    const float* whh = dir ? w_hh_b : w_hh_f;
    float wR[128];
    #pragma unroll
    for (int qq = 0; qq < 32; qq++) {
        float4 v = *(const float4*)(whh + (size_t)r * 128 + qq * 4);
        wR[4*qq+0] = v.x; wR[4*qq+1] = v.y; wR[4*qq+2] = v.z; wR[4*qq+3] = v.w;
    }

    __shared__ __align__(16) float h_lds[2][128];    // 1 KB
    __shared__ __align__(16) float wt_s[KK * 132];   // 4.6 KB (padded)
    __shared__ __align__(16) float em_s[TT * KK];    // 18.4 KB
    __shared__ __align__(16) float h_tile[64 * 132]; // 33.8 KB (padded)
    __shared__ unsigned char bp[TT][KK];             // 4.6 KB   => 61.1 KB total

    float c;
    if (init) {
        c = 0.0f;
        if (q == 0) h_lds[0][k] = 0.0f;
    } else {
        c = c_state[((size_t)dir * 128 + b) * 128 + k];
        if (q == 0) h_lds[0][k] = h_state[((size_t)dir * 128 + b) * 128 + k];
    }
    __syncthreads();                     // h_lds[0] visible

    const float* buf = dir ? buf_b : buf_f;
    const int t0     = dir ? t0b : t0f;
    const int  tl0   = dir ? (C - 1) : 0;
    const long lstep = dir ? -(long)(128 * 512) : (long)(128 * 512);

    const float* xp = buf + ((size_t)tl0 * 128 + b) * 512 + r;
    float xw = *xp;
    float h_reg = 0.0f;

    float* hdst = h_all + (size_t)(dir * BB + b) * TT * 128;   // private region

    for (int s = 0; s < C; s++) {
        const int t = t0 + (dir ? (C - 1 - s) : s);
        const int p = s & 1;
        const float* hprev = h_lds[p];

        float a0 = 0.f, a1 = 0.f, a2 = 0.f, a3 = 0.f;
        #pragma unroll
        for (int qq = 0; qq < 32; qq++) {
            float4 h4 = *(const float4*)&hprev[4 * qq];
            a0 += wR[4*qq+0] * h4.x;
            a1 += wR[4*qq+1] * h4.y;
            a2 += wR[4*qq+2] * h4.z;
            a3 += wR[4*qq+3] * h4.w;
        }
        float pre = xw + ((a0 + a1) + (a2 + a3));

        float act = (q == 2) ? fast_tanh(pre) : fast_sigmoid(pre);

        float f_ = __shfl_xor(act, 1);   // q0 <- q1 (f)
        float g_ = __shfl_xor(act, 2);   // q0 <- q2 (g)
        float o_ = __shfl_xor(act, 3);   // q0 <- q3 (o)

        c = f_ * c + act * g_;           // act == i on q0
        h_reg = o_ * fast_tanh(c);
        if (q == 0) h_lds[p ^ 1][k] = h_reg;

        __syncthreads();                 // h_t visible to all waves

        // post-barrier: issue global ops with a full step of slack
        if (s + 1 < C) { xp += lstep; xw = *xp; }
        if (q == 0)
            hdst[(size_t)t * 128 + k] = h_reg;
    }

    if (q == 0) {
        h_state[((size_t)dir * 128 + b) * 128 + k] = h_reg;
        c_state[((size_t)dir * 128 + b) * 128 + k] = c;
    }

    if (!tail) return;                   // chunked path: only last round decodes

    // ---- phase C: staged, coalesced emission GEMM -------------------------
    // stage this direction's W_tag half (padded rows)
    for (int f = j; f < KK * 128; f += 512)
        wt_s[(f >> 7) * 132 + (f & 127)] = W_tag[(f >> 7) * 256 + dir * 128 + (f & 127)];

    float* emdst = emB + (size_t)b * TT * KK;

    for (int tile = 0; tile < TT / 64; tile++) {
        const int tb = tile * 64;
        // barrier: prev tile's compute done; 1st iter: wt_s staged + each
        // wave's final hdst stores drained (vmcnt(0) before s_barrier)
        __syncthreads();
        #pragma unroll
        for (int it = 0; it < 4; it++) {
            const int f4 = it * 512 + j;         // float4 index in tile
            const int tr = f4 >> 5;              // 32 float4 per row
            const int c4 = (f4 & 31) * 4;
            float4 v = *(const float4*)(hdst + (size_t)(tb + tr) * 128 + c4);
            *(float4*)&h_tile[tr * 132 + c4] = v;
        }
        __syncthreads();                 // tile staged
        for (int task = j; task < 64 * KK; task += 512) {
            const int tl = task / 9;
            const int kk = task - tl * 9;
            const float* hp = &h_tile[tl * 132];
            const float* wp = &wt_s[kk * 132];
            float acc = 0.0f;
            #pragma unroll
            for (int i4 = 0; i4 < 32; i4++) {
                float4 h4 = *(const float4*)(hp + i4 * 4);
                float4 w4 = *(const float4*)(wp + i4 * 4);
                acc += h4.x * w4.x + h4.y * w4.y + h4.z * w4.z + h4.w * w4.w;
            }
            // em index = (tb+tl)*KK + kk = tb*KK + task  (task = tl*9+kk)
            if (dir == 1) emdst[(size_t)tb * KK + task] = acc;   // coalesced
            else          em_s[tb * KK + task] = acc;
        }
    }
    __syncthreads();                     // last tile done; emB stores drained

    if (dir == 1) {                      // backward: publish and exit
        if (j == 0) {
            __threadfence();             // agent-scope: emB visible device-wide
            __hip_atomic_fetch_add(&flags[b], 1u, __ATOMIC_RELEASE,
                                   __HIP_MEMORY_SCOPE_AGENT);
        }
        return;
    }

    // forward: wait for the backward partner's half, fold emB + bias
    if (j == 0) {
        while (__hip_atomic_load(&flags[b], __ATOMIC_ACQUIRE,
                                 __HIP_MEMORY_SCOPE_AGENT) == snap)
            __builtin_amdgcn_s_sleep(1);
    }
    __syncthreads();                     // acquire visible to whole block
    for (int f = j; f < TT * KK; f += 512)
        em_s[f] += emdst[f] + b_tag[f % KK];
    __syncthreads();

    // ---- phase V: Viterbi decode on wave 0 (unchanged, proven) ------------
    if (j < 64) {
        const int lane = j;

        float trans_col[KK];
        float score = -1e30f;
        if (lane < KK) {
            #pragma unroll
            for (int i = 0; i < KK; i++) trans_col[i] = trans[i * KK + lane];
            score = start_trans[lane] + em_s[lane];
        }

        float em_cur = (lane < KK) ? em_s[KK + lane] : 0.0f;   // t=1
        for (int t = 1; t < TT; t++) {
            float em_next = (t + 1 < TT && lane < KK) ? em_s[(t + 1) * KK + lane] : 0.0f;

            float my = (lane < KK) ? score : -1e30f;
            float cand[KK];
            #pragma unroll
            for (int i = 0; i < KK; i++) cand[i] = __shfl(my, i) + trans_col[i];

            float v01, v23, v45, v67, v03, v47, v07, vb_;
            int   i01, i23, i45, i67, i03, i47, i07, ib_;
            {
                bool gt;
                gt = cand[1] > cand[0]; v01 = gt ? cand[1] : cand[0]; i01 = gt ? 1 : 0;
                gt = cand[3] > cand[2]; v23 = gt ? cand[3] : cand[2]; i23 = gt ? 3 : 2;
                gt = cand[5] > cand[4]; v45 = gt ? cand[5] : cand[4]; i45 = gt ? 5 : 4;
                gt = cand[7] > cand[6]; v67 = gt ? cand[7] : cand[6]; i67 = gt ? 7 : 6;
                gt = v23 > v01; v03 = gt ? v23 : v01; i03 = gt ? i23 : i01;
                gt = v67 > v45; v47 = gt ? v67 : v45; i47 = gt ? i67 : i45;
                gt = v47 > v03; v07 = gt ? v47 : v03; i07 = gt ? i47 : i03;
                gt = cand[8] > v07; vb_ = gt ? cand[8] : v07; ib_ = gt ? 8 : i07;
            }

            if (lane < KK) {
                bp[t][lane] = (unsigned char)ib_;
                score = vb_ + em_cur;
            }
            em_cur = em_next;
        }

        float fin = (lane < KK) ? (score + end_trans[lane]) : -1e30f;
        float farr[KK];
        #pragma unroll
        for (int jx = 0; jx < KK; jx++) farr[jx] = __shfl(fin, jx);
        float v01, v23, v45, v67, v03, v47, v07, vb_;
        int   i01, i23, i45, i67, i03, i47, i07, bj;
        {
            bool gt;
            gt = farr[1] > farr[0]; v01 = gt ? farr[1] : farr[0]; i01 = gt ? 1 : 0;
            gt = farr[3] > farr[2]; v23 = gt ? farr[3] : farr[2]; i23 = gt ? 3 : 2;
            gt = farr[5] > farr[4]; v45 = gt ? farr[5] : farr[4]; i45 = gt ? 5 : 4;
            gt = farr[7] > farr[6]; v67 = gt ? farr[7] : farr[6]; i67 = gt ? 7 : 6;
            gt = v23 > v01; v03 = gt ? v23 : v01; i03 = gt ? i23 : i01;
            gt = v67 > v45; v47 = gt ? v67 : v45; i47 = gt ? i67 : i45;
            gt = v47 > v03; v07 = gt ? v47 : v03; i07 = gt ? i47 : i03;
            gt = farr[8] > v07; vb_ = gt ? farr[8] : v07; bj = gt ? 8 : i07;
        }

        if (lane == 0) {
            int tag = bj;
            out[b * TT + (TT - 1)] = tag;
            for (int t = TT - 1; t >= 1; t--) {
                tag = bp[t][tag];
                out[b * TT + t - 1] = tag;
            }
        }
    }
}

// ---------------------------------------------------------------------------
extern "C" void kernel_launch(void* const* d_in, const int* in_sizes, int n_in,
                              void* d_out, int out_size, void* d_ws, size_t ws_size,
                              hipStream_t stream)
{
    const int*   x       = (const int*)  d_in[0];
    const float* emb     = (const float*)d_in[1];
    const float* w_ih_f  = (const float*)d_in[2];
    const float* w_hh_f  = (const float*)d_in[3];
    const float* b_ih_f  = (const float*)d_in[4];
    const float* b_hh_f  = (const float*)d_in[5];
    const float* w_ih_b  = (const float*)d_in[6];
    const float* w_hh_b  = (const float*)d_in[7];
    const float* b_ih_b  = (const float*)d_in[8];
    const float* b_hh_b  = (const float*)d_in[9];
    const float* W_tag   = (const float*)d_in[10];
    const float* b_tag   = (const float*)d_in[11];
    const float* start_t = (const float*)d_in[12];
    const float* end_t   = (const float*)d_in[13];
    const float* trans   = (const float*)d_in[14];
    int* out = (int*)d_out;

    const size_t em_elems    = (size_t)BB * TT * KK;       // 2.25 MB
    const size_t state_elems = (size_t)2 * 128 * 128;
    const size_t hall_elems  = (size_t)2 * BB * TT * 128;  // 67 MB, [dir][b][t][k]

    // C=512 preferred: single lstm dispatch (fixed dispatch cost ~52us).
    int C = 32;
    const int cands[5] = {512, 256, 128, 64, 32};
    for (int ci = 0; ci < 5; ci++) {
        size_t need = ((size_t)2 * cands[ci] * BB * 512
                       + em_elems + 2 * state_elems + hall_elems) * sizeof(float)
                      + 1024;
        if (ws_size >= need) { C = cands[ci]; break; }
    }

    float* buf_f   = (float*)d_ws;                        // C*128*512
    float* buf_b   = buf_f + (size_t)C * BB * 512;        // C*128*512
    float* emB     = buf_b + (size_t)C * BB * 512;        // B*T*9
    float* h_state = emB + em_elems;                      // 2*128*128
    float* c_state = h_state + state_elems;               // 2*128*128
    float* h_all   = c_state + state_elems;               // 2*B*T*128
    unsigned* flags = (unsigned*)(h_all + hall_elems);    // 128 monotonic ctrs

    const int rounds = TT / C;
    for (int r = 0; r < rounds; r++) {
        const int t0f = r * C;
        const int t0b = TT - (r + 1) * C;
        dim3 gg(C, 4, 2);
        input_gemm<<<gg, dim3(256), 0, stream>>>(
            x, emb, w_ih_f, w_ih_b, b_ih_f, b_hh_f, b_ih_b, b_hh_b,
            buf_f, buf_b, t0f, t0b);
        lstm_fused<<<dim3(256), dim3(512), 0, stream>>>(
            buf_f, buf_b, w_hh_f, w_hh_b, h_all,
            h_state, c_state,
            W_tag, b_tag, start_t, end_t, trans,
            emB, flags, out,
            t0f, t0b, C, (r == 0) ? 1 : 0, (r == rounds - 1) ? 1 : 0);
    }
}